// Round 1
// baseline (512.391 us; speedup 1.0000x reference)
//
#include <hip/hip_runtime.h>

// ---------------------------------------------------------------------------
// Mamba2 layer forward, MI355X (gfx950).
// Sizes (compile-time): H=2048 DI=4096 N=128 NH=64 P=64 K=4 CH=256 L=4096
// conv_dim = DI+2N = 4352;  W_in rows = 4416 (padded to 4480 for 128-tiles)
// ---------------------------------------------------------------------------

typedef __bf16 bf16;
typedef __bf16 bf16x8 __attribute__((ext_vector_type(8)));
typedef float  f32x4  __attribute__((ext_vector_type(4)));

#define DEV static __device__ __forceinline__

DEV f32x4 mfma16(bf16x8 a, bf16x8 b, f32x4 c) {
  return __builtin_amdgcn_mfma_f32_16x16x32_bf16(a, b, c, 0, 0, 0);
}

DEV void gll16(const bf16* g, bf16* l) {
  __builtin_amdgcn_global_load_lds(
      (const __attribute__((address_space(1))) unsigned int*)g,
      (__attribute__((address_space(3))) unsigned int*)l, 16, 0, 0);
}

// ---------------------------------------------------------------------------
// Generic bf16 GEMM, B-transposed input:  C[M][N] = A[M][K] * B[N][K]^T
// m97 structure: 128x128 tile, BK=32, 4 waves, global_load_lds width 16.
// ---------------------------------------------------------------------------
template <int K>
__global__ __launch_bounds__(256) void gemm_bt_kernel(
    const bf16* __restrict__ A, const bf16* __restrict__ B,
    float* __restrict__ C, int N) {
  __shared__ bf16 lA[128 * 32];
  __shared__ bf16 lB[128 * 32];
  const int tid = threadIdx.x;
  const int wave = tid >> 6, lane = tid & 63;
  const int lrow = lane & 15, lk = (lane >> 4) * 8;
  const int row0 = blockIdx.x * 128;
  const int col0 = blockIdx.y * 128;
  const int wr = (wave >> 1) * 64, wc = (wave & 1) * 64;
  f32x4 acc[4][4] = {};
  for (int k0 = 0; k0 < K; k0 += 32) {
    __syncthreads();
    for (int j = 0; j < 2; ++j) {
      int seg = wave * 2 + j;
      int e = seg * 512 + lane * 8;   // element in row-major [128][32]
      int r = e >> 5, kk = e & 31;
      gll16(A + (size_t)(row0 + r) * K + (k0 + kk), lA + seg * 512);
      gll16(B + (size_t)(col0 + r) * K + (k0 + kk), lB + seg * 512);
    }
    __syncthreads();
    bf16x8 aF[4], bF[4];
    for (int m = 0; m < 4; ++m)
      aF[m] = *(const bf16x8*)(lA + (wr + m * 16 + lrow) * 32 + lk);
    for (int n = 0; n < 4; ++n)
      bF[n] = *(const bf16x8*)(lB + (wc + n * 16 + lrow) * 32 + lk);
    for (int m = 0; m < 4; ++m)
      for (int n = 0; n < 4; ++n)
        acc[m][n] = mfma16(aF[m], bF[n], acc[m][n]);
  }
  const int orow = (lane >> 4) * 4;
  for (int m = 0; m < 4; ++m)
    for (int n = 0; n < 4; ++n)
      for (int i = 0; i < 4; ++i) {
        int r = row0 + wr + m * 16 + orow + i;
        int c = col0 + wc + n * 16 + lrow;
        C[(size_t)r * N + c] = acc[m][n][i];
      }
}

// ---------------------------------------------------------------------------
// Casts
// ---------------------------------------------------------------------------
__global__ __launch_bounds__(256) void cast_f2b_kernel(
    const float* __restrict__ in, bf16* __restrict__ out, long n) {
  long i = (long)blockIdx.x * blockDim.x + threadIdx.x;
  long stride = (long)gridDim.x * blockDim.x;
  for (; i < n; i += stride) out[i] = (bf16)in[i];
}

__global__ __launch_bounds__(256) void cast_pad_kernel(
    const float* __restrict__ in, bf16* __restrict__ out, long n, long valid) {
  long i = (long)blockIdx.x * blockDim.x + threadIdx.x;
  long stride = (long)gridDim.x * blockDim.x;
  for (; i < n; i += stride) out[i] = (i < valid) ? (bf16)in[i] : (bf16)0.f;
}

// ---------------------------------------------------------------------------
// dt = clip(softplus(raw + dt_bias)), dA = -exp(A_log)*dt, per-chunk inclusive
// cumsum Acs, expAcs = exp(Acs), decayO = exp(Acs[last]-Acs), csum[c][h].
// One block per (chunk, head); 256 threads = chunk positions.
// ---------------------------------------------------------------------------
__global__ __launch_bounds__(256) void dt_scan_kernel(
    const float* __restrict__ xBCdt, const float* __restrict__ dt_bias,
    const float* __restrict__ A_log, float* __restrict__ dt,
    float* __restrict__ Acs, float* __restrict__ decayO,
    float* __restrict__ expAcs, float* __restrict__ csum) {
  const int c = blockIdx.x, h = blockIdx.y;
  const int k = threadIdx.x;
  const int t = c * 256 + k;
  __shared__ float buf[256];
  float raw = xBCdt[(size_t)t * 4480 + 4352 + h] + dt_bias[h];
  float dtv = raw > 20.f ? raw : log1pf(__expf(raw));
  dtv = fminf(fmaxf(dtv, 0.001f), 100.f);
  dt[(size_t)t * 64 + h] = dtv;
  float dA = -__expf(A_log[h]) * dtv;
  buf[k] = dA;
  __syncthreads();
  for (int off = 1; off < 256; off <<= 1) {
    float add = (k >= off) ? buf[k - off] : 0.f;
    __syncthreads();
    buf[k] += add;
    __syncthreads();
  }
  float v = buf[k];
  float total = buf[255];
  size_t base = (size_t)(c * 64 + h) * 256 + k;
  Acs[base] = v;
  expAcs[base] = __expf(v);
  decayO[base] = __expf(total - v);
  if (k == 0) csum[c * 64 + h] = total;
}

// ---------------------------------------------------------------------------
// Depthwise causal conv (K=4) + bias + SiLU over xBC channels.
// Block tile: 64 t x 64 c. Outputs:
//   c in [0,4096):    XS[t][c] (bf16),  XDT_T[h][p][t] = silu*dt (bf16)
//   c in [4096,4224): Bm[t][n] and B_T[n][t]
//   c in [4224,4352): Cm[t][n]
// ---------------------------------------------------------------------------
__global__ __launch_bounds__(256) void conv_kernel(
    const float* __restrict__ xBCdt, const float* __restrict__ conv_w,
    const float* __restrict__ conv_b, const float* __restrict__ dt,
    bf16* __restrict__ XS, bf16* __restrict__ XDT_T, bf16* __restrict__ Bm,
    bf16* __restrict__ BT, bf16* __restrict__ Cm) {
  const int t0 = blockIdx.x * 64;
  const int c0 = blockIdx.y * 64;
  __shared__ float lin[67 * 64];
  __shared__ bf16 tr[64 * 72];
  const int tid = threadIdx.x;
  for (int idx = tid; idx < 67 * 64; idx += 256) {
    int r = idx >> 6, cc = idx & 63;
    int gt = t0 + r - 3;
    lin[idx] = (gt >= 0) ? xBCdt[(size_t)gt * 4480 + c0 + cc] : 0.f;
  }
  __syncthreads();
  const int cl = tid & 63, tg = tid >> 6;
  const int ch = c0 + cl;
  const float w0 = conv_w[ch * 4 + 0], w1 = conv_w[ch * 4 + 1];
  const float w2 = conv_w[ch * 4 + 2], w3 = conv_w[ch * 4 + 3];
  const float bb = conv_b[ch];
  float vals[16];
  for (int j = 0; j < 16; ++j) {
    int tl = tg * 16 + j;
    float s = bb + lin[tl * 64 + cl] * w0 + lin[(tl + 1) * 64 + cl] * w1 +
              lin[(tl + 2) * 64 + cl] * w2 + lin[(tl + 3) * 64 + cl] * w3;
    vals[j] = s / (1.f + __expf(-s));  // silu
  }
  if (c0 < 4096) {
    const int hh = c0 >> 6;  // whole block is one head; cl == p
    for (int j = 0; j < 16; ++j) {
      int t = t0 + tg * 16 + j;
      XS[(size_t)t * 4096 + ch] = (bf16)vals[j];
    }
    __syncthreads();
    for (int j = 0; j < 16; ++j) {
      int tl = tg * 16 + j;
      float dtv = dt[(size_t)(t0 + tl) * 64 + hh];
      tr[cl * 72 + tl] = (bf16)(vals[j] * dtv);
    }
    __syncthreads();
    int p = tid >> 2, toff = (tid & 3) * 16;
    bf16* dst = XDT_T + (size_t)(hh * 64 + p) * 4096 + t0 + toff;
    *(bf16x8*)(dst) = *(const bf16x8*)(tr + p * 72 + toff);
    *(bf16x8*)(dst + 8) = *(const bf16x8*)(tr + p * 72 + toff + 8);
  } else if (c0 < 4224) {
    const int n0 = c0 - 4096;
    for (int j = 0; j < 16; ++j) {
      int t = t0 + tg * 16 + j;
      Bm[(size_t)t * 128 + n0 + cl] = (bf16)vals[j];
    }
    __syncthreads();
    for (int j = 0; j < 16; ++j) tr[cl * 72 + tg * 16 + j] = (bf16)vals[j];
    __syncthreads();
    int p = tid >> 2, toff = (tid & 3) * 16;
    bf16* dst = BT + (size_t)(n0 + p) * 4096 + t0 + toff;
    *(bf16x8*)(dst) = *(const bf16x8*)(tr + p * 72 + toff);
    *(bf16x8*)(dst + 8) = *(const bf16x8*)(tr + p * 72 + toff + 8);
  } else {
    const int n0 = c0 - 4224;
    for (int j = 0; j < 16; ++j) {
      int t = t0 + tg * 16 + j;
      Cm[(size_t)t * 128 + n0 + cl] = (bf16)vals[j];
    }
  }
}

// ---------------------------------------------------------------------------
// G[c][k][s] = sum_n Cm[c*256+k][n] * Bm[c*256+s][n]   (per-chunk C @ B^T)
// grid (16 chunks, 2 k-tiles, 2 s-tiles); 128x128 per block.
// ---------------------------------------------------------------------------
__global__ __launch_bounds__(256) void gmat_kernel(
    const bf16* __restrict__ Cm, const bf16* __restrict__ Bm,
    float* __restrict__ G) {
  const int c = blockIdx.x, kt = blockIdx.y, st = blockIdx.z;
  const int tid = threadIdx.x;
  const int wave = tid >> 6, lane = tid & 63;
  const int lrow = lane & 15, lk = (lane >> 4) * 8;
  const int wr = (wave >> 1) * 64, wc = (wave & 1) * 64;
  f32x4 acc[4][4] = {};
  for (int kk = 0; kk < 4; ++kk) {
    bf16x8 aF[4], bF[4];
    for (int m = 0; m < 4; ++m)
      aF[m] = *(const bf16x8*)(Cm + (size_t)(c * 256 + kt * 128 + wr + m * 16 + lrow) * 128 + kk * 32 + lk);
    for (int n = 0; n < 4; ++n)
      bF[n] = *(const bf16x8*)(Bm + (size_t)(c * 256 + st * 128 + wc + n * 16 + lrow) * 128 + kk * 32 + lk);
    for (int m = 0; m < 4; ++m)
      for (int n = 0; n < 4; ++n)
        acc[m][n] = mfma16(aF[m], bF[n], acc[m][n]);
  }
  const int orow = (lane >> 4) * 4;
  for (int m = 0; m < 4; ++m)
    for (int n = 0; n < 4; ++n)
      for (int i = 0; i < 4; ++i) {
        int k = kt * 128 + wr + m * 16 + orow + i;
        int s = st * 128 + wc + n * 16 + lrow;
        G[((size_t)c * 256 + k) * 256 + s] = acc[m][n][i];
      }
}

// ---------------------------------------------------------------------------
// states[c][h][p][n] = sum_k (xdt_T[h][p][c*256+k]*decayO[c,h,k]) * B_T[n][c*256+k]
// One block per (c,h); A' built in LDS (scaled), B from B_T global.
// ---------------------------------------------------------------------------
__global__ __launch_bounds__(256) void states_kernel(
    const bf16* __restrict__ XDT_T, const bf16* __restrict__ BT,
    const float* __restrict__ decayO, float* __restrict__ states) {
  const int c = blockIdx.x, h = blockIdx.y;
  __shared__ bf16 Ap[64 * 264];
  __shared__ float sDec[256];
  const int tid = threadIdx.x;
  const int wave = tid >> 6, lane = tid & 63;
  const int lrow = lane & 15, lk = (lane >> 4) * 8;
  sDec[tid] = decayO[(size_t)(c * 64 + h) * 256 + tid];
  __syncthreads();
  {
    int p = tid >> 2, kb = (tid & 3) * 64;
    const bf16* src = XDT_T + (size_t)(h * 64 + p) * 4096 + c * 256 + kb;
    for (int j = 0; j < 8; ++j) {
      bf16x8 v = *(const bf16x8*)(src + j * 8);
      bf16x8 o;
      for (int i = 0; i < 8; ++i) o[i] = (bf16)((float)v[i] * sDec[kb + j * 8 + i]);
      *(bf16x8*)(Ap + p * 264 + kb + j * 8) = o;
    }
  }
  __syncthreads();
  const int nb = wave * 32;
  f32x4 acc[4][2] = {};
  for (int kk = 0; kk < 8; ++kk) {
    bf16x8 aF[4], bF[2];
    for (int m = 0; m < 4; ++m)
      aF[m] = *(const bf16x8*)(Ap + (m * 16 + lrow) * 264 + kk * 32 + lk);
    for (int n = 0; n < 2; ++n)
      bF[n] = *(const bf16x8*)(BT + (size_t)(nb + n * 16 + lrow) * 4096 + c * 256 + kk * 32 + lk);
    for (int m = 0; m < 4; ++m)
      for (int n = 0; n < 2; ++n)
        acc[m][n] = mfma16(aF[m], bF[n], acc[m][n]);
  }
  float* st = states + (size_t)(c * 64 + h) * 64 * 128;
  const int orow = (lane >> 4) * 4;
  for (int m = 0; m < 4; ++m)
    for (int n = 0; n < 2; ++n)
      for (int i = 0; i < 4; ++i)
        st[(size_t)(m * 16 + orow + i) * 128 + nb + n * 16 + lrow] = acc[m][n][i];
}

// ---------------------------------------------------------------------------
// Inter-chunk recurrence: prev[c] = exp(csum[c-1])*prev[c-1] + states[c-1]
// ---------------------------------------------------------------------------
__global__ __launch_bounds__(128) void chunk_rec_kernel(
    const float* __restrict__ states, const float* __restrict__ csum,
    bf16* __restrict__ prev) {
  const int h = blockIdx.x, p = blockIdx.y;
  const int n = threadIdx.x;
  size_t base = (size_t)h * 64 * 128 + (size_t)p * 128 + n;
  float run = 0.f;
  for (int c = 0; c < 16; ++c) {
    size_t idx = (size_t)c * 64 * 64 * 128 + base;
    prev[idx] = (bf16)run;
    run = run * __expf(csum[c * 64 + h]) + states[idx];
  }
}

// ---------------------------------------------------------------------------
// Y[t][h*64+p] = Y_off + Y_diag + XS*D, per (chunk, head) block.
//  Y_off = (Cm @ prev^T) * expAcs[k];  Y_diag = M @ XDT with
//  M[k][s] = G[c][k][s]*exp(Acs[k]-Acs[s]) masked s<=k (built per s-tile).
// ---------------------------------------------------------------------------
__global__ __launch_bounds__(256) void ydiag_kernel(
    const bf16* __restrict__ Cm, const bf16* __restrict__ prev,
    const float* __restrict__ G, const float* __restrict__ Acs,
    const float* __restrict__ expAcs, const bf16* __restrict__ XDT_T,
    const bf16* __restrict__ XS, const float* __restrict__ Dp,
    float* __restrict__ Y) {
  const int c = blockIdx.x, h = blockIdx.y;
  __shared__ float sAcs[256];
  __shared__ float sExp[256];
  __shared__ bf16 Ms[256 * 72];
  const int tid = threadIdx.x;
  const int wave = tid >> 6, lane = tid & 63;
  const int lrow = lane & 15, lk = (lane >> 4) * 8;
  sAcs[tid] = Acs[(size_t)(c * 64 + h) * 256 + tid];
  sExp[tid] = expAcs[(size_t)(c * 64 + h) * 256 + tid];
  __syncthreads();
  const int kr = wave * 64;
  f32x4 acc[4][4] = {};
  // --- Y_off: A = Cm rows, B = prev[c][h][p][n] ---
  const bf16* prevb = prev + (size_t)(c * 64 + h) * 64 * 128;
  for (int kk = 0; kk < 4; ++kk) {
    bf16x8 aF[4], bF[4];
    for (int m = 0; m < 4; ++m)
      aF[m] = *(const bf16x8*)(Cm + (size_t)(c * 256 + kr + m * 16 + lrow) * 128 + kk * 32 + lk);
    for (int n = 0; n < 4; ++n)
      bF[n] = *(const bf16x8*)(prevb + (size_t)(n * 16 + lrow) * 128 + kk * 32 + lk);
    for (int m = 0; m < 4; ++m)
      for (int n = 0; n < 4; ++n)
        acc[m][n] = mfma16(aF[m], bF[n], acc[m][n]);
  }
  // scale Y_off rows by exp(Acs[k])
  const int orow = (lane >> 4) * 4;
  for (int m = 0; m < 4; ++m)
    for (int i = 0; i < 4; ++i) {
      float e = sExp[kr + m * 16 + orow + i];
      for (int n = 0; n < 4; ++n) acc[m][n][i] *= e;
    }
  // --- Y_diag over 4 s-tiles of 64 ---
  const float* Gp = G + (size_t)c * 256 * 256;
  for (int stile = 0; stile < 4; ++stile) {
    const int s0 = stile * 64;
    __syncthreads();
    {
      int s_l = tid & 63;
      int s = s0 + s_l;
      float as = sAcs[s];
      for (int k = tid >> 6; k < 256; k += 4) {
        float v = 0.f;
        if (s <= k) v = Gp[(size_t)k * 256 + s] * __expf(sAcs[k] - as);
        Ms[k * 72 + s_l] = (bf16)v;
      }
    }
    __syncthreads();
    if (kr + 63 >= s0) {
      for (int kk = 0; kk < 2; ++kk) {
        bf16x8 aF[4], bF[4];
        for (int m = 0; m < 4; ++m)
          aF[m] = *(const bf16x8*)(Ms + (kr + m * 16 + lrow) * 72 + kk * 32 + lk);
        for (int n = 0; n < 4; ++n)
          bF[n] = *(const bf16x8*)(XDT_T + (size_t)(h * 64 + n * 16 + lrow) * 4096 + c * 256 + s0 + kk * 32 + lk);
        for (int m = 0; m < 4; ++m)
          for (int n = 0; n < 4; ++n)
            acc[m][n] = mfma16(aF[m], bF[n], acc[m][n]);
      }
    }
  }
  // --- epilogue: + x_ssm * D, write Y (f32) ---
  const float Dh = Dp[h];
  for (int m = 0; m < 4; ++m)
    for (int n = 0; n < 4; ++n)
      for (int i = 0; i < 4; ++i) {
        int t = c * 256 + kr + m * 16 + orow + i;
        int col = h * 64 + n * 16 + lrow;
        float xs = (float)XS[(size_t)t * 4096 + col];
        Y[(size_t)t * 4096 + col] = acc[m][n][i] + xs * Dh;
      }
}

// ---------------------------------------------------------------------------
// RMSNorm over DI=4096 per row; writes bf16 for GEMM2.
// ---------------------------------------------------------------------------
__global__ __launch_bounds__(256) void rmsnorm_kernel(
    const float* __restrict__ Y, const float* __restrict__ norm_w,
    bf16* __restrict__ out) {
  const int row = blockIdx.x;
  const float* y = Y + (size_t)row * 4096;
  float ss = 0.f;
  for (int j = threadIdx.x; j < 4096; j += 256) {
    float v = y[j];
    ss += v * v;
  }
  for (int off = 32; off; off >>= 1) ss += __shfl_down(ss, off, 64);
  __shared__ float ws[4];
  if ((threadIdx.x & 63) == 0) ws[threadIdx.x >> 6] = ss;
  __syncthreads();
  float tot = ws[0] + ws[1] + ws[2] + ws[3];
  float scale = rsqrtf(tot / 4096.f + 1e-6f);
  for (int j = threadIdx.x; j < 4096; j += 256)
    out[(size_t)row * 4096 + j] = (bf16)(y[j] * scale * norm_w[j]);
}

// ---------------------------------------------------------------------------
extern "C" void kernel_launch(void* const* d_in, const int* in_sizes, int n_in,
                              void* d_out, int out_size, void* d_ws, size_t ws_size,
                              hipStream_t stream) {
  const float* x       = (const float*)d_in[0];
  const float* W_in    = (const float*)d_in[1];
  const float* conv_w  = (const float*)d_in[2];
  const float* conv_b  = (const float*)d_in[3];
  const float* dt_bias = (const float*)d_in[4];
  const float* A_log   = (const float*)d_in[5];
  const float* Dp      = (const float*)d_in[6];
  const float* norm_w  = (const float*)d_in[7];
  const float* W_out   = (const float*)d_in[8];

  size_t o = 0;
  char* base = (char*)d_ws;
  auto take = [&](size_t b) {
    char* p = base + o;
    o += (b + 255) & ~(size_t)255;
    return (void*)p;
  };
  bf16*  xb     = (bf16*)take((size_t)4096 * 2048 * 2);   // 16.8 MB
  bf16*  winb   = (bf16*)take((size_t)4480 * 2048 * 2);   // 18.35 MB
  float* xBCdt  = (float*)take((size_t)4096 * 4480 * 4);  // 73.4 MB
  float* dtg    = (float*)take((size_t)4096 * 64 * 4);
  float* Acs    = (float*)take((size_t)4096 * 64 * 4);
  float* decayO = (float*)take((size_t)4096 * 64 * 4);
  float* expA   = (float*)take((size_t)4096 * 64 * 4);
  float* csum   = (float*)take((size_t)16 * 64 * 4);
  bf16*  XS     = (bf16*)take((size_t)4096 * 4096 * 2);   // 33.6 MB
  bf16*  XDT_T  = (bf16*)take((size_t)4096 * 4096 * 2);   // 33.6 MB
  bf16*  Bm     = (bf16*)take((size_t)4096 * 128 * 2);
  bf16*  BT     = (bf16*)take((size_t)4096 * 128 * 2);
  bf16*  Cm     = (bf16*)take((size_t)4096 * 128 * 2);
  float* G      = (float*)take((size_t)16 * 256 * 256 * 4);
  float* states = (float*)take((size_t)16 * 64 * 64 * 128 * 4);  // 33.6 MB
  bf16*  prev   = (bf16*)take((size_t)16 * 64 * 64 * 128 * 2);   // 16.8 MB
  // aliases (lifetimes disjoint):
  bf16*  ynorm  = xb;              // over xb+winb (35.1 MB >= 33.6 MB)
  float* Y      = xBCdt;           // 67 MB <= 73.4 MB
  bf16*  woutb  = (bf16*)states;   // cast launched after states' last read

  // 1) casts for GEMM1
  cast_f2b_kernel<<<2048, 256, 0, stream>>>(x, xb, (long)4096 * 2048);
  cast_pad_kernel<<<2048, 256, 0, stream>>>(W_in, winb, (long)4480 * 2048,
                                            (long)4416 * 2048);
  // 2) GEMM1: xBCdt = x @ W_in^T   (M=4096, N=4480, K=2048)
  gemm_bt_kernel<2048><<<dim3(32, 35), 256, 0, stream>>>(xb, winb, xBCdt, 4480);
  // 3) dt + per-chunk cumsum
  dt_scan_kernel<<<dim3(16, 64), 256, 0, stream>>>(xBCdt, dt_bias, A_log, dtg,
                                                   Acs, decayO, expA, csum);
  // 4) conv + silu + layout builds
  conv_kernel<<<dim3(64, 68), 256, 0, stream>>>(xBCdt, conv_w, conv_b, dtg, XS,
                                                XDT_T, Bm, BT, Cm);
  // 5) G = C @ B^T per chunk
  gmat_kernel<<<dim3(16, 2, 2), 256, 0, stream>>>(Cm, Bm, G);
  // 6) intra-chunk states
  states_kernel<<<dim3(16, 64), 256, 0, stream>>>(XDT_T, BT, decayO, states);
  // 7) inter-chunk recurrence -> prev (bf16)
  chunk_rec_kernel<<<dim3(64, 64), 128, 0, stream>>>(states, csum, prev);
  // 8) W_out cast (states now dead; woutb aliases it)
  cast_f2b_kernel<<<2048, 256, 0, stream>>>(W_out, woutb, (long)2048 * 4096);
  // 9) Y = Y_diag + Y_off + XS*D
  ydiag_kernel<<<dim3(16, 64), 256, 0, stream>>>(Cm, prev, G, Acs, expA, XDT_T,
                                                 XS, Dp, Y);
  // 10) RMSNorm -> bf16
  rmsnorm_kernel<<<4096, 256, 0, stream>>>(Y, norm_w, ynorm);
  // 11) GEMM2: out = ynorm @ W_out^T  (M=4096, N=2048, K=4096)
  gemm_bt_kernel<4096><<<dim3(32, 16), 256, 0, stream>>>(ynorm, woutb,
                                                         (float*)d_out, 2048);
}

// Round 2
// 455.917 us; speedup vs baseline: 1.1239x; 1.1239x over previous
//
#include <hip/hip_runtime.h>

// ---------------------------------------------------------------------------
// Mamba2 layer forward, MI355X (gfx950).
// Sizes (compile-time): H=2048 DI=4096 N=128 NH=64 P=64 K=4 CH=256 L=4096
// conv_dim = DI+2N = 4352;  W_in rows = 4416 (padded to 4480 for 128-tiles)
// ---------------------------------------------------------------------------

typedef __bf16 bf16;
typedef __bf16 bf16x8 __attribute__((ext_vector_type(8)));
typedef __bf16 bf16x4 __attribute__((ext_vector_type(4)));
typedef float  f32x4  __attribute__((ext_vector_type(4)));

#define DEV static __device__ __forceinline__

DEV f32x4 mfma16(bf16x8 a, bf16x8 b, f32x4 c) {
  return __builtin_amdgcn_mfma_f32_16x16x32_bf16(a, b, c, 0, 0, 0);
}

DEV void gll16(const bf16* g, bf16* l) {
  __builtin_amdgcn_global_load_lds(
      (const __attribute__((address_space(1))) unsigned int*)g,
      (__attribute__((address_space(3))) unsigned int*)l, 16, 0, 0);
}

// ---------------------------------------------------------------------------
// Generic bf16 GEMM, B-transposed input:  C[M][N] = A[M][K] * B[N][K]^T
// m97 structure + XCD-bijective block swizzle (nwg % 8 == 0 for both uses).
// ---------------------------------------------------------------------------
template <int K, int GX>
__global__ __launch_bounds__(256) void gemm_bt_kernel(
    const bf16* __restrict__ A, const bf16* __restrict__ B,
    float* __restrict__ C, int N, int nwg) {
  const int cpx = nwg >> 3;
  const int swz = (blockIdx.x & 7) * cpx + (blockIdx.x >> 3);
  const int bx = swz % GX, by = swz / GX;
  __shared__ bf16 lA[128 * 32];
  __shared__ bf16 lB[128 * 32];
  const int tid = threadIdx.x;
  const int wave = tid >> 6, lane = tid & 63;
  const int lrow = lane & 15, lk = (lane >> 4) * 8;
  const int row0 = bx * 128;
  const int col0 = by * 128;
  const int wr = (wave >> 1) * 64, wc = (wave & 1) * 64;
  f32x4 acc[4][4] = {};
  for (int k0 = 0; k0 < K; k0 += 32) {
    __syncthreads();
    for (int j = 0; j < 2; ++j) {
      int seg = wave * 2 + j;
      int e = seg * 512 + lane * 8;   // element in row-major [128][32]
      int r = e >> 5, kk = e & 31;
      gll16(A + (size_t)(row0 + r) * K + (k0 + kk), lA + seg * 512);
      gll16(B + (size_t)(col0 + r) * K + (k0 + kk), lB + seg * 512);
    }
    __syncthreads();
    bf16x8 aF[4], bF[4];
    for (int m = 0; m < 4; ++m)
      aF[m] = *(const bf16x8*)(lA + (wr + m * 16 + lrow) * 32 + lk);
    for (int n = 0; n < 4; ++n)
      bF[n] = *(const bf16x8*)(lB + (wc + n * 16 + lrow) * 32 + lk);
    for (int m = 0; m < 4; ++m)
      for (int n = 0; n < 4; ++n)
        acc[m][n] = mfma16(aF[m], bF[n], acc[m][n]);
  }
  const int orow = (lane >> 4) * 4;
  for (int m = 0; m < 4; ++m)
    for (int n = 0; n < 4; ++n)
      for (int i = 0; i < 4; ++i) {
        int r = row0 + wr + m * 16 + orow + i;
        int c = col0 + wc + n * 16 + lrow;
        C[(size_t)r * N + c] = acc[m][n][i];
      }
}

// ---------------------------------------------------------------------------
// Casts (vectorized: float4 -> bf16x4). Element counts are multiples of 4.
// ---------------------------------------------------------------------------
__global__ __launch_bounds__(256) void cast_f2b_kernel(
    const float* __restrict__ in, bf16* __restrict__ out, long n4) {
  long i = (long)blockIdx.x * blockDim.x + threadIdx.x;
  long stride = (long)gridDim.x * blockDim.x;
  for (; i < n4; i += stride) {
    float4 v = ((const float4*)in)[i];
    bf16x4 o = {(bf16)v.x, (bf16)v.y, (bf16)v.z, (bf16)v.w};
    ((bf16x4*)out)[i] = o;
  }
}

__global__ __launch_bounds__(256) void cast_pad_kernel(
    const float* __restrict__ in, bf16* __restrict__ out, long n4, long valid4) {
  long i = (long)blockIdx.x * blockDim.x + threadIdx.x;
  long stride = (long)gridDim.x * blockDim.x;
  for (; i < n4; i += stride) {
    bf16x4 o = {(bf16)0.f, (bf16)0.f, (bf16)0.f, (bf16)0.f};
    if (i < valid4) {
      float4 v = ((const float4*)in)[i];
      o = bf16x4{(bf16)v.x, (bf16)v.y, (bf16)v.z, (bf16)v.w};
    }
    ((bf16x4*)out)[i] = o;
  }
}

// ---------------------------------------------------------------------------
// dt = clip(softplus(raw + dt_bias)), dA = -exp(A_log)*dt, per-chunk inclusive
// cumsum Acs, expAcs = exp(Acs), decayO = exp(Acs[last]-Acs), csum[c][h].
// ---------------------------------------------------------------------------
__global__ __launch_bounds__(256) void dt_scan_kernel(
    const float* __restrict__ xBCdt, const float* __restrict__ dt_bias,
    const float* __restrict__ A_log, float* __restrict__ dt,
    float* __restrict__ Acs, float* __restrict__ decayO,
    float* __restrict__ expAcs, float* __restrict__ csum) {
  const int c = blockIdx.x, h = blockIdx.y;
  const int k = threadIdx.x;
  const int t = c * 256 + k;
  __shared__ float buf[256];
  float raw = xBCdt[(size_t)t * 4480 + 4352 + h] + dt_bias[h];
  float dtv = raw > 20.f ? raw : log1pf(__expf(raw));
  dtv = fminf(fmaxf(dtv, 0.001f), 100.f);
  dt[(size_t)t * 64 + h] = dtv;
  float dA = -__expf(A_log[h]) * dtv;
  buf[k] = dA;
  __syncthreads();
  for (int off = 1; off < 256; off <<= 1) {
    float add = (k >= off) ? buf[k - off] : 0.f;
    __syncthreads();
    buf[k] += add;
    __syncthreads();
  }
  float v = buf[k];
  float total = buf[255];
  size_t base = (size_t)(c * 64 + h) * 256 + k;
  Acs[base] = v;
  expAcs[base] = __expf(v);
  decayO[base] = __expf(total - v);
  if (k == 0) csum[c * 64 + h] = total;
}

// ---------------------------------------------------------------------------
// Depthwise causal conv (K=4) + bias + SiLU over xBC channels.
// ---------------------------------------------------------------------------
__global__ __launch_bounds__(256) void conv_kernel(
    const float* __restrict__ xBCdt, const float* __restrict__ conv_w,
    const float* __restrict__ conv_b, const float* __restrict__ dt,
    bf16* __restrict__ XS, bf16* __restrict__ XDT_T, bf16* __restrict__ Bm,
    bf16* __restrict__ BT, bf16* __restrict__ Cm) {
  const int t0 = blockIdx.x * 64;
  const int c0 = blockIdx.y * 64;
  __shared__ float lin[67 * 64];
  __shared__ bf16 tr[64 * 72];
  const int tid = threadIdx.x;
  for (int idx = tid; idx < 67 * 64; idx += 256) {
    int r = idx >> 6, cc = idx & 63;
    int gt = t0 + r - 3;
    lin[idx] = (gt >= 0) ? xBCdt[(size_t)gt * 4480 + c0 + cc] : 0.f;
  }
  __syncthreads();
  const int cl = tid & 63, tg = tid >> 6;
  const int ch = c0 + cl;
  const float w0 = conv_w[ch * 4 + 0], w1 = conv_w[ch * 4 + 1];
  const float w2 = conv_w[ch * 4 + 2], w3 = conv_w[ch * 4 + 3];
  const float bb = conv_b[ch];
  float vals[16];
  for (int j = 0; j < 16; ++j) {
    int tl = tg * 16 + j;
    float s = bb + lin[tl * 64 + cl] * w0 + lin[(tl + 1) * 64 + cl] * w1 +
              lin[(tl + 2) * 64 + cl] * w2 + lin[(tl + 3) * 64 + cl] * w3;
    vals[j] = s / (1.f + __expf(-s));  // silu
  }
  if (c0 < 4096) {
    const int hh = c0 >> 6;  // whole block is one head; cl == p
    for (int j = 0; j < 16; ++j) {
      int t = t0 + tg * 16 + j;
      XS[(size_t)t * 4096 + ch] = (bf16)vals[j];
    }
    __syncthreads();
    for (int j = 0; j < 16; ++j) {
      int tl = tg * 16 + j;
      float dtv = dt[(size_t)(t0 + tl) * 64 + hh];
      tr[cl * 72 + tl] = (bf16)(vals[j] * dtv);
    }
    __syncthreads();
    int p = tid >> 2, toff = (tid & 3) * 16;
    bf16* dst = XDT_T + (size_t)(hh * 64 + p) * 4096 + t0 + toff;
    *(bf16x8*)(dst) = *(const bf16x8*)(tr + p * 72 + toff);
    *(bf16x8*)(dst + 8) = *(const bf16x8*)(tr + p * 72 + toff + 8);
  } else if (c0 < 4224) {
    const int n0 = c0 - 4096;
    for (int j = 0; j < 16; ++j) {
      int t = t0 + tg * 16 + j;
      Bm[(size_t)t * 128 + n0 + cl] = (bf16)vals[j];
    }
    __syncthreads();
    for (int j = 0; j < 16; ++j) tr[cl * 72 + tg * 16 + j] = (bf16)vals[j];
    __syncthreads();
    int p = tid >> 2, toff = (tid & 3) * 16;
    bf16* dst = BT + (size_t)(n0 + p) * 4096 + t0 + toff;
    *(bf16x8*)(dst) = *(const bf16x8*)(tr + p * 72 + toff);
    *(bf16x8*)(dst + 8) = *(const bf16x8*)(tr + p * 72 + toff + 8);
  } else {
    const int n0 = c0 - 4224;
    for (int j = 0; j < 16; ++j) {
      int t = t0 + tg * 16 + j;
      Cm[(size_t)t * 128 + n0 + cl] = (bf16)vals[j];
    }
  }
}

// ---------------------------------------------------------------------------
// G[c][k][s] = sum_n Cm[c*256+k][n] * Bm[c*256+s][n]   (per-chunk C @ B^T)
// ---------------------------------------------------------------------------
__global__ __launch_bounds__(256) void gmat_kernel(
    const bf16* __restrict__ Cm, const bf16* __restrict__ Bm,
    float* __restrict__ G) {
  const int c = blockIdx.x, kt = blockIdx.y, st = blockIdx.z;
  const int tid = threadIdx.x;
  const int wave = tid >> 6, lane = tid & 63;
  const int lrow = lane & 15, lk = (lane >> 4) * 8;
  const int wr = (wave >> 1) * 64, wc = (wave & 1) * 64;
  f32x4 acc[4][4] = {};
  for (int kk = 0; kk < 4; ++kk) {
    bf16x8 aF[4], bF[4];
    for (int m = 0; m < 4; ++m)
      aF[m] = *(const bf16x8*)(Cm + (size_t)(c * 256 + kt * 128 + wr + m * 16 + lrow) * 128 + kk * 32 + lk);
    for (int n = 0; n < 4; ++n)
      bF[n] = *(const bf16x8*)(Bm + (size_t)(c * 256 + st * 128 + wc + n * 16 + lrow) * 128 + kk * 32 + lk);
    for (int m = 0; m < 4; ++m)
      for (int n = 0; n < 4; ++n)
        acc[m][n] = mfma16(aF[m], bF[n], acc[m][n]);
  }
  const int orow = (lane >> 4) * 4;
  for (int m = 0; m < 4; ++m)
    for (int n = 0; n < 4; ++n)
      for (int i = 0; i < 4; ++i) {
        int k = kt * 128 + wr + m * 16 + orow + i;
        int s = st * 128 + wc + n * 16 + lrow;
        G[((size_t)c * 256 + k) * 256 + s] = acc[m][n][i];
      }
}

// ---------------------------------------------------------------------------
// states[c][h][p][n] = sum_k (xdt_T[h][p][k]*decayO[c,h,k]) * B_T[n][k]
// ---------------------------------------------------------------------------
__global__ __launch_bounds__(256) void states_kernel(
    const bf16* __restrict__ XDT_T, const bf16* __restrict__ BT,
    const float* __restrict__ decayO, float* __restrict__ states) {
  const int c = blockIdx.x, h = blockIdx.y;
  __shared__ bf16 Ap[64 * 264];
  __shared__ float sDec[256];
  const int tid = threadIdx.x;
  const int wave = tid >> 6, lane = tid & 63;
  const int lrow = lane & 15, lk = (lane >> 4) * 8;
  sDec[tid] = decayO[(size_t)(c * 64 + h) * 256 + tid];
  __syncthreads();
  {
    int p = tid >> 2, kb = (tid & 3) * 64;
    const bf16* src = XDT_T + (size_t)(h * 64 + p) * 4096 + c * 256 + kb;
    for (int j = 0; j < 8; ++j) {
      bf16x8 v = *(const bf16x8*)(src + j * 8);
      bf16x8 o;
      for (int i = 0; i < 8; ++i) o[i] = (bf16)((float)v[i] * sDec[kb + j * 8 + i]);
      *(bf16x8*)(Ap + p * 264 + kb + j * 8) = o;
    }
  }
  __syncthreads();
  const int nb = wave * 32;
  f32x4 acc[4][2] = {};
  for (int kk = 0; kk < 8; ++kk) {
    bf16x8 aF[4], bF[2];
    for (int m = 0; m < 4; ++m)
      aF[m] = *(const bf16x8*)(Ap + (m * 16 + lrow) * 264 + kk * 32 + lk);
    for (int n = 0; n < 2; ++n)
      bF[n] = *(const bf16x8*)(BT + (size_t)(nb + n * 16 + lrow) * 4096 + c * 256 + kk * 32 + lk);
    for (int m = 0; m < 4; ++m)
      for (int n = 0; n < 2; ++n)
        acc[m][n] = mfma16(aF[m], bF[n], acc[m][n]);
  }
  float* st = states + (size_t)(c * 64 + h) * 64 * 128;
  const int orow = (lane >> 4) * 4;
  for (int m = 0; m < 4; ++m)
    for (int n = 0; n < 2; ++n)
      for (int i = 0; i < 4; ++i)
        st[(size_t)(m * 16 + orow + i) * 128 + nb + n * 16 + lrow] = acc[m][n][i];
}

// ---------------------------------------------------------------------------
// Inter-chunk recurrence: prev[c] = exp(csum[c-1])*prev[c-1] + states[c-1]
// ---------------------------------------------------------------------------
__global__ __launch_bounds__(128) void chunk_rec_kernel(
    const float* __restrict__ states, const float* __restrict__ csum,
    bf16* __restrict__ prev) {
  const int h = blockIdx.x, p = blockIdx.y;
  const int n = threadIdx.x;
  size_t base = (size_t)h * 64 * 128 + (size_t)p * 128 + n;
  float run = 0.f;
  for (int c = 0; c < 16; ++c) {
    size_t idx = (size_t)c * 64 * 64 * 128 + base;
    prev[idx] = (bf16)run;
    run = run * __expf(csum[c * 64 + h]) + states[idx];
  }
}

// ---------------------------------------------------------------------------
// Y = Y_off + Y_diag + XS*D per (chunk, head).  Rewritten:
//  - prev and XDT tiles staged in LDS (coalesced bf16x8), ONE barrier total
//  - M fragments (G * exp(Acs[k]-Acs[s]), causal mask) built in registers
//  - k-rows interleaved across waves (row = m*64 + wave*16) for balance
// ---------------------------------------------------------------------------
__global__ __launch_bounds__(256) void ydiag_kernel(
    const bf16* __restrict__ Cm, const bf16* __restrict__ prev,
    const float* __restrict__ G, const float* __restrict__ Acs,
    const float* __restrict__ expAcs, const bf16* __restrict__ XDT_T,
    const bf16* __restrict__ XS, const float* __restrict__ Dp,
    float* __restrict__ Y) {
  const int c = blockIdx.x, h = blockIdx.y;
  __shared__ float sAcs[256];
  __shared__ float sExp[256];
  __shared__ __align__(16) bf16 pv[64 * 136];  // prev [p][n]
  __shared__ __align__(16) bf16 xd[64 * 264];  // xdt  [p][s]
  const int tid = threadIdx.x;
  const int wave = tid >> 6, lane = tid & 63;
  const int lrow = lane & 15, lk = (lane >> 4) * 8;
  const int wv16 = wave * 16;
  sAcs[tid] = Acs[(size_t)(c * 64 + h) * 256 + tid];
  sExp[tid] = expAcs[(size_t)(c * 64 + h) * 256 + tid];
  {  // stage prev tile: 64 rows x 128 (4 thr/row x 32 elems)
    int r = tid >> 2, q = (tid & 3) * 32;
    const bf16* src = prev + (size_t)(c * 64 + h) * 8192 + r * 128 + q;
    bf16* dst = pv + r * 136 + q;
    for (int j = 0; j < 4; ++j)
      *(bf16x8*)(dst + j * 8) = *(const bf16x8*)(src + j * 8);
  }
  {  // stage xdt tile: 64 rows x 256 (4 thr/row x 64 elems)
    int r = tid >> 2, q = (tid & 3) * 64;
    const bf16* src = XDT_T + (size_t)(h * 64 + r) * 4096 + c * 256 + q;
    bf16* dst = xd + r * 264 + q;
    for (int j = 0; j < 8; ++j)
      *(bf16x8*)(dst + j * 8) = *(const bf16x8*)(src + j * 8);
  }
  __syncthreads();
  f32x4 acc[4][4] = {};
  // --- Y_off: A = Cm rows (global), B = pv (LDS) ---
  __builtin_amdgcn_s_setprio(1);
  for (int kk = 0; kk < 4; ++kk) {
    bf16x8 aF[4], bF[4];
    for (int m = 0; m < 4; ++m)
      aF[m] = *(const bf16x8*)(Cm + (size_t)(c * 256 + m * 64 + wv16 + lrow) * 128 + kk * 32 + lk);
    for (int n = 0; n < 4; ++n)
      bF[n] = *(const bf16x8*)(pv + (n * 16 + lrow) * 136 + kk * 32 + lk);
    for (int m = 0; m < 4; ++m)
      for (int n = 0; n < 4; ++n)
        acc[m][n] = mfma16(aF[m], bF[n], acc[m][n]);
  }
  __builtin_amdgcn_s_setprio(0);
  // scale Y_off rows by exp(Acs[k])
  const int orow = (lane >> 4) * 4;
  for (int m = 0; m < 4; ++m)
    for (int i = 0; i < 4; ++i) {
      float e = sExp[m * 64 + wv16 + orow + i];
      for (int n = 0; n < 4; ++n) acc[m][n][i] *= e;
    }
  // --- Y_diag: register-built decay-masked A fragments ---
  const float* Gp = G + (size_t)c * 65536;
  for (int stile = 0; stile < 4; ++stile) {
    const int s0 = stile * 64;
    for (int kk = 0; kk < 2; ++kk) {
      bf16x8 bF[4];
      for (int n = 0; n < 4; ++n)
        bF[n] = *(const bf16x8*)(xd + (n * 16 + lrow) * 264 + s0 + kk * 32 + lk);
      for (int m = 0; m < 4; ++m) {
        if (m * 64 + wv16 + 15 < s0) continue;  // fragment fully above diagonal
        const int row = m * 64 + wv16 + lrow;
        const float ak = sAcs[row];
        const float* grow = Gp + (size_t)row * 256 + s0 + kk * 32 + lk;
        bf16x8 af;
        for (int j = 0; j < 8; ++j) {
          int s = s0 + kk * 32 + lk + j;
          float v = grow[j] * __expf(ak - sAcs[s]);
          if (s > row) v = 0.f;
          af[j] = (bf16)v;
        }
        __builtin_amdgcn_s_setprio(1);
        for (int n = 0; n < 4; ++n)
          acc[m][n] = mfma16(af, bF[n], acc[m][n]);
        __builtin_amdgcn_s_setprio(0);
      }
    }
  }
  // --- epilogue: + x_ssm * D ---
  const float Dh = Dp[h];
  for (int m = 0; m < 4; ++m)
    for (int n = 0; n < 4; ++n)
      for (int i = 0; i < 4; ++i) {
        int t = c * 256 + m * 64 + wv16 + orow + i;
        int col = h * 64 + n * 16 + lrow;
        float xs = (float)XS[(size_t)t * 4096 + col];
        Y[(size_t)t * 4096 + col] = acc[m][n][i] + xs * Dh;
      }
}

// ---------------------------------------------------------------------------
// RMSNorm over DI=4096 per row (vectorized); writes bf16 for GEMM2.
// ---------------------------------------------------------------------------
__global__ __launch_bounds__(256) void rmsnorm_kernel(
    const float* __restrict__ Y, const float* __restrict__ norm_w,
    bf16* __restrict__ out) {
  const int row = blockIdx.x;
  const float4* y4 = (const float4*)(Y + (size_t)row * 4096);
  float4 v[4];
  float ss = 0.f;
  for (int j = 0; j < 4; ++j) {
    v[j] = y4[threadIdx.x + j * 256];
    ss += v[j].x * v[j].x + v[j].y * v[j].y + v[j].z * v[j].z + v[j].w * v[j].w;
  }
  for (int off = 32; off; off >>= 1) ss += __shfl_down(ss, off, 64);
  __shared__ float ws[4];
  if ((threadIdx.x & 63) == 0) ws[threadIdx.x >> 6] = ss;
  __syncthreads();
  float scale = rsqrtf((ws[0] + ws[1] + ws[2] + ws[3]) / 4096.f + 1e-6f);
  for (int j = 0; j < 4; ++j) {
    int col = (threadIdx.x + j * 256) * 4;
    float4 w = *(const float4*)(norm_w + col);
    bf16x4 o = {(bf16)(v[j].x * scale * w.x), (bf16)(v[j].y * scale * w.y),
                (bf16)(v[j].z * scale * w.z), (bf16)(v[j].w * scale * w.w)};
    *(bf16x4*)(out + (size_t)row * 4096 + col) = o;
  }
}

// ---------------------------------------------------------------------------
extern "C" void kernel_launch(void* const* d_in, const int* in_sizes, int n_in,
                              void* d_out, int out_size, void* d_ws, size_t ws_size,
                              hipStream_t stream) {
  const float* x       = (const float*)d_in[0];
  const float* W_in    = (const float*)d_in[1];
  const float* conv_w  = (const float*)d_in[2];
  const float* conv_b  = (const float*)d_in[3];
  const float* dt_bias = (const float*)d_in[4];
  const float* A_log   = (const float*)d_in[5];
  const float* Dp      = (const float*)d_in[6];
  const float* norm_w  = (const float*)d_in[7];
  const float* W_out   = (const float*)d_in[8];

  size_t o = 0;
  char* base = (char*)d_ws;
  auto take = [&](size_t b) {
    char* p = base + o;
    o += (b + 255) & ~(size_t)255;
    return (void*)p;
  };
  bf16*  xb     = (bf16*)take((size_t)4096 * 2048 * 2);
  bf16*  winb   = (bf16*)take((size_t)4480 * 2048 * 2);
  float* xBCdt  = (float*)take((size_t)4096 * 4480 * 4);
  float* dtg    = (float*)take((size_t)4096 * 64 * 4);
  float* Acs    = (float*)take((size_t)4096 * 64 * 4);
  float* decayO = (float*)take((size_t)4096 * 64 * 4);
  float* expA   = (float*)take((size_t)4096 * 64 * 4);
  float* csum   = (float*)take((size_t)16 * 64 * 4);
  bf16*  XS     = (bf16*)take((size_t)4096 * 4096 * 2);
  bf16*  XDT_T  = (bf16*)take((size_t)4096 * 4096 * 2);
  bf16*  Bm     = (bf16*)take((size_t)4096 * 128 * 2);
  bf16*  BT     = (bf16*)take((size_t)4096 * 128 * 2);
  bf16*  Cm     = (bf16*)take((size_t)4096 * 128 * 2);
  float* G      = (float*)take((size_t)16 * 256 * 256 * 4);
  float* states = (float*)take((size_t)16 * 64 * 64 * 128 * 4);
  bf16*  prev   = (bf16*)take((size_t)16 * 64 * 64 * 128 * 2);
  // aliases (lifetimes disjoint):
  bf16*  ynorm  = xb;              // over xb+winb (35.1 MB >= 33.6 MB)
  float* Y      = xBCdt;           // 67 MB <= 73.4 MB
  bf16*  woutb  = (bf16*)states;   // cast launched after states' last read

  // 1) casts for GEMM1
  cast_f2b_kernel<<<2048, 256, 0, stream>>>(x, xb, (long)4096 * 2048 / 4);
  cast_pad_kernel<<<2048, 256, 0, stream>>>(W_in, winb, (long)4480 * 2048 / 4,
                                            (long)4416 * 2048 / 4);
  // 2) GEMM1: xBCdt = x @ W_in^T   (M=4096, N=4480, K=2048), 1120 blocks
  gemm_bt_kernel<2048, 32><<<1120, 256, 0, stream>>>(xb, winb, xBCdt, 4480, 1120);
  // 3) dt + per-chunk cumsum
  dt_scan_kernel<<<dim3(16, 64), 256, 0, stream>>>(xBCdt, dt_bias, A_log, dtg,
                                                   Acs, decayO, expA, csum);
  // 4) conv + silu + layout builds
  conv_kernel<<<dim3(64, 68), 256, 0, stream>>>(xBCdt, conv_w, conv_b, dtg, XS,
                                                XDT_T, Bm, BT, Cm);
  // 5) G = C @ B^T per chunk
  gmat_kernel<<<dim3(16, 2, 2), 256, 0, stream>>>(Cm, Bm, G);
  // 6) intra-chunk states
  states_kernel<<<dim3(16, 64), 256, 0, stream>>>(XDT_T, BT, decayO, states);
  // 7) inter-chunk recurrence -> prev (bf16)
  chunk_rec_kernel<<<dim3(64, 64), 128, 0, stream>>>(states, csum, prev);
  // 8) W_out cast (states now dead; woutb aliases it)
  cast_f2b_kernel<<<2048, 256, 0, stream>>>(W_out, woutb, (long)2048 * 4096 / 4);
  // 9) Y = Y_diag + Y_off + XS*D
  ydiag_kernel<<<dim3(16, 64), 256, 0, stream>>>(Cm, prev, G, Acs, expA, XDT_T,
                                                 XS, Dp, Y);
  // 10) RMSNorm -> bf16
  rmsnorm_kernel<<<4096, 256, 0, stream>>>(Y, norm_w, ynorm);
  // 11) GEMM2: out = ynorm @ W_out^T  (M=4096, N=2048, K=4096), 512 blocks
  gemm_bt_kernel<4096, 32><<<512, 256, 0, stream>>>(ynorm, woutb,
                                                    (float*)d_out, 2048, 512);
}

// Round 3
// 396.752 us; speedup vs baseline: 1.2915x; 1.1491x over previous
//
#include <hip/hip_runtime.h>

// ---------------------------------------------------------------------------
// Mamba2 layer forward, MI355X (gfx950).
// Sizes (compile-time): H=2048 DI=4096 N=128 NH=64 P=64 K=4 CH=256 L=4096
// conv_dim = DI+2N = 4352;  W_in rows = 4416 (padded to 4480 for 128-tiles)
// ---------------------------------------------------------------------------

typedef __bf16 bf16;
typedef __bf16 bf16x8 __attribute__((ext_vector_type(8)));
typedef __bf16 bf16x4 __attribute__((ext_vector_type(4)));
typedef float  f32x4  __attribute__((ext_vector_type(4)));

#define DEV static __device__ __forceinline__

DEV f32x4 mfma16(bf16x8 a, bf16x8 b, f32x4 c) {
  return __builtin_amdgcn_mfma_f32_16x16x32_bf16(a, b, c, 0, 0, 0);
}

DEV void gll16(const bf16* g, bf16* l) {
  __builtin_amdgcn_global_load_lds(
      (const __attribute__((address_space(1))) unsigned int*)g,
      (__attribute__((address_space(3))) unsigned int*)l, 16, 0, 0);
}

#define BAR()   asm volatile("s_barrier" ::: "memory")
#define LGKM0() do { asm volatile("s_waitcnt lgkmcnt(0)" ::: "memory"); \
                     __builtin_amdgcn_sched_barrier(0); } while (0)
#define VMW(n)  asm volatile("s_waitcnt vmcnt(" #n ")" ::: "memory")

// ---------------------------------------------------------------------------
// Pipelined bf16 GEMM, B-transposed:  C[M][N] = A[M][K] * B[N][K]^T
// BM=256 BN=128 BK=64, 8 waves (wave-tile 64x64), ring-3 LDS (144KB),
// XOR-swizzled LDS (both sides: pre-swizzled global src + swizzled ds_read),
// 4 phases per K-tile, counted vmcnt(6) across barriers (never 0 in loop).
// ---------------------------------------------------------------------------
template <int K>
__global__ __launch_bounds__(512) void gemm8p_kernel(
    const bf16* __restrict__ A, const bf16* __restrict__ B,
    float* __restrict__ C, int N, int ntN) {
  constexpr int NT = K / 64;
  // per slot: A 256x64 bf16 (32768 B) + B 128x64 bf16 (16384 B) = 49152 B
  __shared__ __align__(16) bf16 lds[3 * 24576];
  const int tid = threadIdx.x;
  const int wave = tid >> 6, lane = tid & 63;
  const int lrow = lane & 15;
  const int lkb = (lane >> 4) * 16;        // byte offset of k-group in 128B row
  const int xorv = (lrow & 7) << 4;        // swizzle key for frag reads
  const int bx = blockIdx.x / ntN, by = blockIdx.x % ntN;
  const int row0 = bx * 256, col0 = by * 128;
  const int arow = (wave >> 1) * 64;       // wave's A row band
  const int brow = (wave & 1) * 64;        // wave's B row band (= C col band)

  // staging source pointers, pre-swizzled so linear LDS dest = swizzled layout
  const bf16* gA[4];
  const bf16* gB[2];
#pragma unroll
  for (int r = 0; r < 4; ++r) {
    int P = r * 8192 + tid * 16;
    int L = P ^ (((P >> 7) & 7) << 4);
    gA[r] = A + (size_t)(row0 + (L >> 7)) * K + ((L & 127) >> 1);
  }
#pragma unroll
  for (int r = 0; r < 2; ++r) {
    int P = r * 8192 + tid * 16;
    int L = P ^ (((P >> 7) & 7) << 4);
    gB[r] = B + (size_t)(col0 + (L >> 7)) * K + ((L & 127) >> 1);
  }
  const int ldsW = wave * 512;  // per-wave element offset inside a 4096-elem round

  // frag readers (swizzled LDS byte addressing)
  auto rdA = [&](int slB, int m, int ks) -> bf16x8 {
    return *(const bf16x8*)((const char*)lds + slB +
                            (arow + m * 16 + lrow) * 128 +
                            (((ks << 6) | lkb) ^ xorv));
  };
  auto rdB = [&](int slB, int n, int ks) -> bf16x8 {
    return *(const bf16x8*)((const char*)lds + slB + 32768 +
                            (brow + n * 16 + lrow) * 128 +
                            (((ks << 6) | lkb) ^ xorv));
  };
  auto stA01 = [&](int ss) {
    gll16(gA[0], lds + ss * 24576 + 0 * 4096 + ldsW);
    gll16(gA[1], lds + ss * 24576 + 1 * 4096 + ldsW);
  };
  auto stA23 = [&](int ss) {
    gll16(gA[2], lds + ss * 24576 + 2 * 4096 + ldsW);
    gll16(gA[3], lds + ss * 24576 + 3 * 4096 + ldsW);
  };
  auto stB = [&](int ss) {
    gll16(gB[0], lds + ss * 24576 + 16384 + 0 * 4096 + ldsW);
    gll16(gB[1], lds + ss * 24576 + 16384 + 1 * 4096 + ldsW);
  };
  auto adv = [&]() {
#pragma unroll
    for (int r = 0; r < 4; ++r) gA[r] += 64;
#pragma unroll
    for (int r = 0; r < 2; ++r) gB[r] += 64;
  };

  f32x4 acc[4][4] = {};
  bf16x8 aF[4][2], bF[4][2];

  // prologue: stage tiles 0 and 1
  stA01(0); stA23(0); stB(0); adv();
  stA01(1); stA23(1); stB(1); adv();
  VMW(6);   // tile 0 landed (6 of 12 retired)
  BAR();

  int sl = 0, ss = 2;
  for (int t = 0; t < NT; ++t) {
    const int slB = sl * 49152;
    const bool pf = (t + 2 < NT);
    // ---- P0: read a0,a1,b0,b1; stage A01(t+2) ----
#pragma unroll
    for (int m = 0; m < 2; ++m)
#pragma unroll
      for (int ks = 0; ks < 2; ++ks) aF[m][ks] = rdA(slB, m, ks);
#pragma unroll
    for (int n = 0; n < 2; ++n)
#pragma unroll
      for (int ks = 0; ks < 2; ++ks) bF[n][ks] = rdB(slB, n, ks);
    if (pf) stA01(ss);
    BAR(); LGKM0();
    __builtin_amdgcn_s_setprio(1);
#pragma unroll
    for (int m = 0; m < 2; ++m)
#pragma unroll
      for (int n = 0; n < 2; ++n)
#pragma unroll
        for (int ks = 0; ks < 2; ++ks)
          acc[m][n] = mfma16(aF[m][ks], bF[n][ks], acc[m][n]);
    __builtin_amdgcn_s_setprio(0);
    __builtin_amdgcn_sched_barrier(0);
    BAR();
    // ---- P1: read b2,b3; stage A23(t+2) ----
#pragma unroll
    for (int n = 2; n < 4; ++n)
#pragma unroll
      for (int ks = 0; ks < 2; ++ks) bF[n][ks] = rdB(slB, n, ks);
    if (pf) stA23(ss);
    BAR(); LGKM0();
    __builtin_amdgcn_s_setprio(1);
#pragma unroll
    for (int m = 0; m < 2; ++m)
#pragma unroll
      for (int n = 2; n < 4; ++n)
#pragma unroll
        for (int ks = 0; ks < 2; ++ks)
          acc[m][n] = mfma16(aF[m][ks], bF[n][ks], acc[m][n]);
    __builtin_amdgcn_s_setprio(0);
    __builtin_amdgcn_sched_barrier(0);
    BAR();
    // ---- P2: read a2,a3; stage B(t+2) ----
#pragma unroll
    for (int m = 2; m < 4; ++m)
#pragma unroll
      for (int ks = 0; ks < 2; ++ks) aF[m][ks] = rdA(slB, m, ks);
    if (pf) { stB(ss); adv(); }
    BAR(); LGKM0();
    __builtin_amdgcn_s_setprio(1);
#pragma unroll
    for (int m = 2; m < 4; ++m)
#pragma unroll
      for (int n = 0; n < 2; ++n)
#pragma unroll
        for (int ks = 0; ks < 2; ++ks)
          acc[m][n] = mfma16(aF[m][ks], bF[n][ks], acc[m][n]);
    __builtin_amdgcn_s_setprio(0);
    __builtin_amdgcn_sched_barrier(0);
    BAR();
    // ---- P3: last quadrant; counted vmcnt before tile-end barrier ----
    __builtin_amdgcn_s_setprio(1);
#pragma unroll
    for (int m = 2; m < 4; ++m)
#pragma unroll
      for (int n = 2; n < 4; ++n)
#pragma unroll
        for (int ks = 0; ks < 2; ++ks)
          acc[m][n] = mfma16(aF[m][ks], bF[n][ks], acc[m][n]);
    __builtin_amdgcn_s_setprio(0);
    __builtin_amdgcn_sched_barrier(0);
    if (t < NT - 2) { VMW(6); } else { VMW(0); }
    BAR();
    sl = (sl == 2) ? 0 : sl + 1;
    ss = (ss == 2) ? 0 : ss + 1;
  }
  // epilogue: C write (f32)
  const int orow = (lane >> 4) * 4;
#pragma unroll
  for (int m = 0; m < 4; ++m)
#pragma unroll
    for (int n = 0; n < 4; ++n)
#pragma unroll
      for (int i = 0; i < 4; ++i) {
        int r = row0 + arow + m * 16 + orow + i;
        int c = col0 + brow + n * 16 + lrow;
        C[(size_t)r * N + c] = acc[m][n][i];
      }
}

// ---------------------------------------------------------------------------
// Casts (vectorized: float4 -> bf16x4). Element counts are multiples of 4.
// ---------------------------------------------------------------------------
__global__ __launch_bounds__(256) void cast_f2b_kernel(
    const float* __restrict__ in, bf16* __restrict__ out, long n4) {
  long i = (long)blockIdx.x * blockDim.x + threadIdx.x;
  long stride = (long)gridDim.x * blockDim.x;
  for (; i < n4; i += stride) {
    float4 v = ((const float4*)in)[i];
    bf16x4 o = {(bf16)v.x, (bf16)v.y, (bf16)v.z, (bf16)v.w};
    ((bf16x4*)out)[i] = o;
  }
}

__global__ __launch_bounds__(256) void cast_pad_kernel(
    const float* __restrict__ in, bf16* __restrict__ out, long n4, long valid4) {
  long i = (long)blockIdx.x * blockDim.x + threadIdx.x;
  long stride = (long)gridDim.x * blockDim.x;
  for (; i < n4; i += stride) {
    bf16x4 o = {(bf16)0.f, (bf16)0.f, (bf16)0.f, (bf16)0.f};
    if (i < valid4) {
      float4 v = ((const float4*)in)[i];
      o = bf16x4{(bf16)v.x, (bf16)v.y, (bf16)v.z, (bf16)v.w};
    }
    ((bf16x4*)out)[i] = o;
  }
}

// ---------------------------------------------------------------------------
// dt = clip(softplus(raw + dt_bias)), dA = -exp(A_log)*dt, per-chunk inclusive
// cumsum Acs, expAcs = exp(Acs), decayO = exp(Acs[last]-Acs), csum[c][h].
// ---------------------------------------------------------------------------
__global__ __launch_bounds__(256) void dt_scan_kernel(
    const float* __restrict__ xBCdt, const float* __restrict__ dt_bias,
    const float* __restrict__ A_log, float* __restrict__ dt,
    float* __restrict__ Acs, float* __restrict__ decayO,
    float* __restrict__ expAcs, float* __restrict__ csum) {
  const int c = blockIdx.x, h = blockIdx.y;
  const int k = threadIdx.x;
  const int t = c * 256 + k;
  __shared__ float buf[256];
  float raw = xBCdt[(size_t)t * 4480 + 4352 + h] + dt_bias[h];
  float dtv = raw > 20.f ? raw : log1pf(__expf(raw));
  dtv = fminf(fmaxf(dtv, 0.001f), 100.f);
  dt[(size_t)t * 64 + h] = dtv;
  float dA = -__expf(A_log[h]) * dtv;
  buf[k] = dA;
  __syncthreads();
  for (int off = 1; off < 256; off <<= 1) {
    float add = (k >= off) ? buf[k - off] : 0.f;
    __syncthreads();
    buf[k] += add;
    __syncthreads();
  }
  float v = buf[k];
  float total = buf[255];
  size_t base = (size_t)(c * 64 + h) * 256 + k;
  Acs[base] = v;
  expAcs[base] = __expf(v);
  decayO[base] = __expf(total - v);
  if (k == 0) csum[c * 64 + h] = total;
}

// ---------------------------------------------------------------------------
// Depthwise causal conv (K=4) + bias + SiLU over xBC channels.
// ---------------------------------------------------------------------------
__global__ __launch_bounds__(256) void conv_kernel(
    const float* __restrict__ xBCdt, const float* __restrict__ conv_w,
    const float* __restrict__ conv_b, const float* __restrict__ dt,
    bf16* __restrict__ XS, bf16* __restrict__ XDT_T, bf16* __restrict__ Bm,
    bf16* __restrict__ BT, bf16* __restrict__ Cm) {
  const int t0 = blockIdx.x * 64;
  const int c0 = blockIdx.y * 64;
  __shared__ float lin[67 * 64];
  __shared__ bf16 tr[64 * 72];
  const int tid = threadIdx.x;
  for (int idx = tid; idx < 67 * 64; idx += 256) {
    int r = idx >> 6, cc = idx & 63;
    int gt = t0 + r - 3;
    lin[idx] = (gt >= 0) ? xBCdt[(size_t)gt * 4480 + c0 + cc] : 0.f;
  }
  __syncthreads();
  const int cl = tid & 63, tg = tid >> 6;
  const int ch = c0 + cl;
  const float w0 = conv_w[ch * 4 + 0], w1 = conv_w[ch * 4 + 1];
  const float w2 = conv_w[ch * 4 + 2], w3 = conv_w[ch * 4 + 3];
  const float bb = conv_b[ch];
  float vals[16];
  for (int j = 0; j < 16; ++j) {
    int tl = tg * 16 + j;
    float s = bb + lin[tl * 64 + cl] * w0 + lin[(tl + 1) * 64 + cl] * w1 +
              lin[(tl + 2) * 64 + cl] * w2 + lin[(tl + 3) * 64 + cl] * w3;
    vals[j] = s / (1.f + __expf(-s));  // silu
  }
  if (c0 < 4096) {
    const int hh = c0 >> 6;  // whole block is one head; cl == p
    for (int j = 0; j < 16; ++j) {
      int t = t0 + tg * 16 + j;
      XS[(size_t)t * 4096 + ch] = (bf16)vals[j];
    }
    __syncthreads();
    for (int j = 0; j < 16; ++j) {
      int tl = tg * 16 + j;
      float dtv = dt[(size_t)(t0 + tl) * 64 + hh];
      tr[cl * 72 + tl] = (bf16)(vals[j] * dtv);
    }
    __syncthreads();
    int p = tid >> 2, toff = (tid & 3) * 16;
    bf16* dst = XDT_T + (size_t)(hh * 64 + p) * 4096 + t0 + toff;
    *(bf16x8*)(dst) = *(const bf16x8*)(tr + p * 72 + toff);
    *(bf16x8*)(dst + 8) = *(const bf16x8*)(tr + p * 72 + toff + 8);
  } else if (c0 < 4224) {
    const int n0 = c0 - 4096;
    for (int j = 0; j < 16; ++j) {
      int t = t0 + tg * 16 + j;
      Bm[(size_t)t * 128 + n0 + cl] = (bf16)vals[j];
    }
    __syncthreads();
    for (int j = 0; j < 16; ++j) tr[cl * 72 + tg * 16 + j] = (bf16)vals[j];
    __syncthreads();
    int p = tid >> 2, toff = (tid & 3) * 16;
    bf16* dst = BT + (size_t)(n0 + p) * 4096 + t0 + toff;
    *(bf16x8*)(dst) = *(const bf16x8*)(tr + p * 72 + toff);
    *(bf16x8*)(dst + 8) = *(const bf16x8*)(tr + p * 72 + toff + 8);
  } else {
    const int n0 = c0 - 4224;
    for (int j = 0; j < 16; ++j) {
      int t = t0 + tg * 16 + j;
      Cm[(size_t)t * 128 + n0 + cl] = (bf16)vals[j];
    }
  }
}

// ---------------------------------------------------------------------------
// G[c][k][s] = sum_n Cm[c*256+k][n] * Bm[c*256+s][n]   (per-chunk C @ B^T)
// ---------------------------------------------------------------------------
__global__ __launch_bounds__(256) void gmat_kernel(
    const bf16* __restrict__ Cm, const bf16* __restrict__ Bm,
    float* __restrict__ G) {
  const int c = blockIdx.x, kt = blockIdx.y, st = blockIdx.z;
  const int tid = threadIdx.x;
  const int wave = tid >> 6, lane = tid & 63;
  const int lrow = lane & 15, lk = (lane >> 4) * 8;
  const int wr = (wave >> 1) * 64, wc = (wave & 1) * 64;
  f32x4 acc[4][4] = {};
  for (int kk = 0; kk < 4; ++kk) {
    bf16x8 aF[4], bF[4];
    for (int m = 0; m < 4; ++m)
      aF[m] = *(const bf16x8*)(Cm + (size_t)(c * 256 + kt * 128 + wr + m * 16 + lrow) * 128 + kk * 32 + lk);
    for (int n = 0; n < 4; ++n)
      bF[n] = *(const bf16x8*)(Bm + (size_t)(c * 256 + st * 128 + wc + n * 16 + lrow) * 128 + kk * 32 + lk);
    for (int m = 0; m < 4; ++m)
      for (int n = 0; n < 4; ++n)
        acc[m][n] = mfma16(aF[m], bF[n], acc[m][n]);
  }
  const int orow = (lane >> 4) * 4;
  for (int m = 0; m < 4; ++m)
    for (int n = 0; n < 4; ++n)
      for (int i = 0; i < 4; ++i) {
        int k = kt * 128 + wr + m * 16 + orow + i;
        int s = st * 128 + wc + n * 16 + lrow;
        G[((size_t)c * 256 + k) * 256 + s] = acc[m][n][i];
      }
}

// ---------------------------------------------------------------------------
// states[c][h][p][n] = sum_k (xdt_T[h][p][k]*decayO[c,h,k]) * B_T[n][k]
// ---------------------------------------------------------------------------
__global__ __launch_bounds__(256) void states_kernel(
    const bf16* __restrict__ XDT_T, const bf16* __restrict__ BT,
    const float* __restrict__ decayO, float* __restrict__ states) {
  const int c = blockIdx.x, h = blockIdx.y;
  __shared__ bf16 Ap[64 * 264];
  __shared__ float sDec[256];
  const int tid = threadIdx.x;
  const int wave = tid >> 6, lane = tid & 63;
  const int lrow = lane & 15, lk = (lane >> 4) * 8;
  sDec[tid] = decayO[(size_t)(c * 64 + h) * 256 + tid];
  __syncthreads();
  {
    int p = tid >> 2, kb = (tid & 3) * 64;
    const bf16* src = XDT_T + (size_t)(h * 64 + p) * 4096 + c * 256 + kb;
    for (int j = 0; j < 8; ++j) {
      bf16x8 v = *(const bf16x8*)(src + j * 8);
      bf16x8 o;
      for (int i = 0; i < 8; ++i) o[i] = (bf16)((float)v[i] * sDec[kb + j * 8 + i]);
      *(bf16x8*)(Ap + p * 264 + kb + j * 8) = o;
    }
  }
  __syncthreads();
  const int nb = wave * 32;
  f32x4 acc[4][2] = {};
  for (int kk = 0; kk < 8; ++kk) {
    bf16x8 aF[4], bF[2];
    for (int m = 0; m < 4; ++m)
      aF[m] = *(const bf16x8*)(Ap + (m * 16 + lrow) * 264 + kk * 32 + lk);
    for (int n = 0; n < 2; ++n)
      bF[n] = *(const bf16x8*)(BT + (size_t)(nb + n * 16 + lrow) * 4096 + c * 256 + kk * 32 + lk);
    for (int m = 0; m < 4; ++m)
      for (int n = 0; n < 2; ++n)
        acc[m][n] = mfma16(aF[m], bF[n], acc[m][n]);
  }
  float* st = states + (size_t)(c * 64 + h) * 64 * 128;
  const int orow = (lane >> 4) * 4;
  for (int m = 0; m < 4; ++m)
    for (int n = 0; n < 2; ++n)
      for (int i = 0; i < 4; ++i)
        st[(size_t)(m * 16 + orow + i) * 128 + nb + n * 16 + lrow] = acc[m][n][i];
}

// ---------------------------------------------------------------------------
// Inter-chunk recurrence: prev[c] = exp(csum[c-1])*prev[c-1] + states[c-1]
// ---------------------------------------------------------------------------
__global__ __launch_bounds__(128) void chunk_rec_kernel(
    const float* __restrict__ states, const float* __restrict__ csum,
    bf16* __restrict__ prev) {
  const int h = blockIdx.x, p = blockIdx.y;
  const int n = threadIdx.x;
  size_t base = (size_t)h * 64 * 128 + (size_t)p * 128 + n;
  float run = 0.f;
  for (int c = 0; c < 16; ++c) {
    size_t idx = (size_t)c * 64 * 64 * 128 + base;
    prev[idx] = (bf16)run;
    run = run * __expf(csum[c * 64 + h]) + states[idx];
  }
}

// ---------------------------------------------------------------------------
// Y = Y_off + Y_diag + XS*D per (chunk, head).
// ---------------------------------------------------------------------------
__global__ __launch_bounds__(256) void ydiag_kernel(
    const bf16* __restrict__ Cm, const bf16* __restrict__ prev,
    const float* __restrict__ G, const float* __restrict__ Acs,
    const float* __restrict__ expAcs, const bf16* __restrict__ XDT_T,
    const bf16* __restrict__ XS, const float* __restrict__ Dp,
    float* __restrict__ Y) {
  const int c = blockIdx.x, h = blockIdx.y;
  __shared__ float sAcs[256];
  __shared__ float sExp[256];
  __shared__ __align__(16) bf16 pv[64 * 136];  // prev [p][n]
  __shared__ __align__(16) bf16 xd[64 * 264];  // xdt  [p][s]
  const int tid = threadIdx.x;
  const int wave = tid >> 6, lane = tid & 63;
  const int lrow = lane & 15, lk = (lane >> 4) * 8;
  const int wv16 = wave * 16;
  sAcs[tid] = Acs[(size_t)(c * 64 + h) * 256 + tid];
  sExp[tid] = expAcs[(size_t)(c * 64 + h) * 256 + tid];
  {  // stage prev tile: 64 rows x 128 (4 thr/row x 32 elems)
    int r = tid >> 2, q = (tid & 3) * 32;
    const bf16* src = prev + (size_t)(c * 64 + h) * 8192 + r * 128 + q;
    bf16* dst = pv + r * 136 + q;
    for (int j = 0; j < 4; ++j)
      *(bf16x8*)(dst + j * 8) = *(const bf16x8*)(src + j * 8);
  }
  {  // stage xdt tile: 64 rows x 256 (4 thr/row x 64 elems)
    int r = tid >> 2, q = (tid & 3) * 64;
    const bf16* src = XDT_T + (size_t)(h * 64 + r) * 4096 + c * 256 + q;
    bf16* dst = xd + r * 264 + q;
    for (int j = 0; j < 8; ++j)
      *(bf16x8*)(dst + j * 8) = *(const bf16x8*)(src + j * 8);
  }
  __syncthreads();
  f32x4 acc[4][4] = {};
  // --- Y_off: A = Cm rows (global), B = pv (LDS) ---
  __builtin_amdgcn_s_setprio(1);
  for (int kk = 0; kk < 4; ++kk) {
    bf16x8 aF[4], bF[4];
    for (int m = 0; m < 4; ++m)
      aF[m] = *(const bf16x8*)(Cm + (size_t)(c * 256 + m * 64 + wv16 + lrow) * 128 + kk * 32 + lk);
    for (int n = 0; n < 4; ++n)
      bF[n] = *(const bf16x8*)(pv + (n * 16 + lrow) * 136 + kk * 32 + lk);
    for (int m = 0; m < 4; ++m)
      for (int n = 0; n < 4; ++n)
        acc[m][n] = mfma16(aF[m], bF[n], acc[m][n]);
  }
  __builtin_amdgcn_s_setprio(0);
  // scale Y_off rows by exp(Acs[k])
  const int orow = (lane >> 4) * 4;
  for (int m = 0; m < 4; ++m)
    for (int i = 0; i < 4; ++i) {
      float e = sExp[m * 64 + wv16 + orow + i];
      for (int n = 0; n < 4; ++n) acc[m][n][i] *= e;
    }
  // --- Y_diag: register-built decay-masked A fragments ---
  const float* Gp = G + (size_t)c * 65536;
  for (int stile = 0; stile < 4; ++stile) {
    const int s0 = stile * 64;
    for (int kk = 0; kk < 2; ++kk) {
      bf16x8 bF[4];
      for (int n = 0; n < 4; ++n)
        bF[n] = *(const bf16x8*)(xd + (n * 16 + lrow) * 264 + s0 + kk * 32 + lk);
      for (int m = 0; m < 4; ++m) {
        if (m * 64 + wv16 + 15 < s0) continue;  // fragment fully above diagonal
        const int row = m * 64 + wv16 + lrow;
        const float ak = sAcs[row];
        const float* grow = Gp + (size_t)row * 256 + s0 + kk * 32 + lk;
        bf16x8 af;
        for (int j = 0; j < 8; ++j) {
          int s = s0 + kk * 32 + lk + j;
          float v = grow[j] * __expf(ak - sAcs[s]);
          if (s > row) v = 0.f;
          af[j] = (bf16)v;
        }
        __builtin_amdgcn_s_setprio(1);
        for (int n = 0; n < 4; ++n)
          acc[m][n] = mfma16(af, bF[n], acc[m][n]);
        __builtin_amdgcn_s_setprio(0);
      }
    }
  }
  // --- epilogue: + x_ssm * D ---
  const float Dh = Dp[h];
  for (int m = 0; m < 4; ++m)
    for (int n = 0; n < 4; ++n)
      for (int i = 0; i < 4; ++i) {
        int t = c * 256 + m * 64 + wv16 + orow + i;
        int col = h * 64 + n * 16 + lrow;
        float xs = (float)XS[(size_t)t * 4096 + col];
        Y[(size_t)t * 4096 + col] = acc[m][n][i] + xs * Dh;
      }
}

// ---------------------------------------------------------------------------
// RMSNorm over DI=4096 per row (vectorized); writes bf16 for GEMM2.
// ---------------------------------------------------------------------------
__global__ __launch_bounds__(256) void rmsnorm_kernel(
    const float* __restrict__ Y, const float* __restrict__ norm_w,
    bf16* __restrict__ out) {
  const int row = blockIdx.x;
  const float4* y4 = (const float4*)(Y + (size_t)row * 4096);
  float4 v[4];
  float ss = 0.f;
  for (int j = 0; j < 4; ++j) {
    v[j] = y4[threadIdx.x + j * 256];
    ss += v[j].x * v[j].x + v[j].y * v[j].y + v[j].z * v[j].z + v[j].w * v[j].w;
  }
  for (int off = 32; off; off >>= 1) ss += __shfl_down(ss, off, 64);
  __shared__ float ws[4];
  if ((threadIdx.x & 63) == 0) ws[threadIdx.x >> 6] = ss;
  __syncthreads();
  float scale = rsqrtf((ws[0] + ws[1] + ws[2] + ws[3]) / 4096.f + 1e-6f);
  for (int j = 0; j < 4; ++j) {
    int col = (threadIdx.x + j * 256) * 4;
    float4 w = *(const float4*)(norm_w + col);
    bf16x4 o = {(bf16)(v[j].x * scale * w.x), (bf16)(v[j].y * scale * w.y),
                (bf16)(v[j].z * scale * w.z), (bf16)(v[j].w * scale * w.w)};
    *(bf16x4*)(out + (size_t)row * 4096 + col) = o;
  }
}

// ---------------------------------------------------------------------------
extern "C" void kernel_launch(void* const* d_in, const int* in_sizes, int n_in,
                              void* d_out, int out_size, void* d_ws, size_t ws_size,
                              hipStream_t stream) {
  const float* x       = (const float*)d_in[0];
  const float* W_in    = (const float*)d_in[1];
  const float* conv_w  = (const float*)d_in[2];
  const float* conv_b  = (const float*)d_in[3];
  const float* dt_bias = (const float*)d_in[4];
  const float* A_log   = (const float*)d_in[5];
  const float* Dp      = (const float*)d_in[6];
  const float* norm_w  = (const float*)d_in[7];
  const float* W_out   = (const float*)d_in[8];

  size_t o = 0;
  char* base = (char*)d_ws;
  auto take = [&](size_t b) {
    char* p = base + o;
    o += (b + 255) & ~(size_t)255;
    return (void*)p;
  };
  bf16*  xb     = (bf16*)take((size_t)4096 * 2048 * 2);
  bf16*  winb   = (bf16*)take((size_t)4480 * 2048 * 2);
  float* xBCdt  = (float*)take((size_t)4096 * 4480 * 4);
  float* dtg    = (float*)take((size_t)4096 * 64 * 4);
  float* Acs    = (float*)take((size_t)4096 * 64 * 4);
  float* decayO = (float*)take((size_t)4096 * 64 * 4);
  float* expA   = (float*)take((size_t)4096 * 64 * 4);
  float* csum   = (float*)take((size_t)16 * 64 * 4);
  bf16*  XS     = (bf16*)take((size_t)4096 * 4096 * 2);
  bf16*  XDT_T  = (bf16*)take((size_t)4096 * 4096 * 2);
  bf16*  Bm     = (bf16*)take((size_t)4096 * 128 * 2);
  bf16*  BT     = (bf16*)take((size_t)4096 * 128 * 2);
  bf16*  Cm     = (bf16*)take((size_t)4096 * 128 * 2);
  float* G      = (float*)take((size_t)16 * 256 * 256 * 4);
  float* states = (float*)take((size_t)16 * 64 * 64 * 128 * 4);
  bf16*  prev   = (bf16*)take((size_t)16 * 64 * 64 * 128 * 2);
  // aliases (lifetimes disjoint):
  bf16*  ynorm  = xb;              // over xb+winb (35.1 MB >= 33.6 MB)
  float* Y      = xBCdt;           // 67 MB <= 73.4 MB
  bf16*  woutb  = (bf16*)states;   // cast launched after states' last read

  // 1) casts for GEMM1
  cast_f2b_kernel<<<2048, 256, 0, stream>>>(x, xb, (long)4096 * 2048 / 4);
  cast_pad_kernel<<<2048, 256, 0, stream>>>(W_in, winb, (long)4480 * 2048 / 4,
                                            (long)4416 * 2048 / 4);
  // 2) GEMM1: xBCdt = x @ W_in^T   (M=4096, N=4480, K=2048)
  gemm8p_kernel<2048><<<560, 512, 0, stream>>>(xb, winb, xBCdt, 4480, 35);
  // 3) dt + per-chunk cumsum
  dt_scan_kernel<<<dim3(16, 64), 256, 0, stream>>>(xBCdt, dt_bias, A_log, dtg,
                                                   Acs, decayO, expA, csum);
  // 4) conv + silu + layout builds
  conv_kernel<<<dim3(64, 68), 256, 0, stream>>>(xBCdt, conv_w, conv_b, dtg, XS,
                                                XDT_T, Bm, BT, Cm);
  // 5) G = C @ B^T per chunk
  gmat_kernel<<<dim3(16, 2, 2), 256, 0, stream>>>(Cm, Bm, G);
  // 6) intra-chunk states
  states_kernel<<<dim3(16, 64), 256, 0, stream>>>(XDT_T, BT, decayO, states);
  // 7) inter-chunk recurrence -> prev (bf16)
  chunk_rec_kernel<<<dim3(64, 64), 128, 0, stream>>>(states, csum, prev);
  // 8) W_out cast (states now dead; woutb aliases it)
  cast_f2b_kernel<<<2048, 256, 0, stream>>>(W_out, woutb, (long)2048 * 4096 / 4);
  // 9) Y = Y_diag + Y_off + XS*D
  ydiag_kernel<<<dim3(16, 64), 256, 0, stream>>>(Cm, prev, G, Acs, expA, XDT_T,
                                                 XS, Dp, Y);
  // 10) RMSNorm -> bf16
  rmsnorm_kernel<<<4096, 256, 0, stream>>>(Y, norm_w, ynorm);
  // 11) GEMM2: out = ynorm @ W_out^T  (M=4096, N=2048, K=4096)
  gemm8p_kernel<4096><<<256, 512, 0, stream>>>(ynorm, woutb,
                                               (float*)d_out, 2048, 16);
}